// Round 6
// baseline (26297.766 us; speedup 1.0000x reference)
//
#include <hip/hip_runtime.h>
#include <cstddef>
#include <cstdint>

typedef short s8v   __attribute__((ext_vector_type(8)));   // 8 x bf16 bits
typedef float f32x4 __attribute__((ext_vector_type(4)));

__device__ __forceinline__ float b2f(unsigned short u) {
  union { unsigned u; float f; } x; x.u = ((unsigned)u) << 16; return x.f;
}
__device__ __forceinline__ unsigned short f2b(float f) {
  union { float f; unsigned u; } x; x.f = f;
  unsigned u = x.u;
  return (unsigned short)((u + 0x7FFFu + ((u >> 16) & 1u)) >> 16);  // RNE
}
__device__ __forceinline__ float sigm(float x) { return 1.f / (1.f + __expf(-x)); }
__device__ __forceinline__ float tanh_(float x) { return 1.f - 2.f / (__expf(2.f * x) + 1.f); }

#define AT_LOAD(p)     __hip_atomic_load((p), __ATOMIC_RELAXED, __HIP_MEMORY_SCOPE_AGENT)
#define AT_LOADU(p)    __hip_atomic_load((p), __ATOMIC_RELAXED, __HIP_MEMORY_SCOPE_AGENT)
#define AT_STORE(p,v)  __hip_atomic_store((p), (v), __ATOMIC_RELEASE, __HIP_MEMORY_SCOPE_AGENT)
#define AT_STOREU(p,v) __hip_atomic_store((p), (v), __ATOMIC_RELAXED, __HIP_MEMORY_SCOPE_AGENT)

// ---------------------------------------------------------------------------
// Embedding gather + f32->bf16
// ---------------------------------------------------------------------------
__global__ void __launch_bounds__(256)
k_embed(const int* __restrict__ tok, const float* __restrict__ emb,
        unsigned short* __restrict__ x1)
{
  const int g = blockIdx.x * 256 + threadIdx.x;
  if (g >= 64 * 512 * 8) return;
  const int row = g >> 3, i = g & 7;
  const int t = tok[row];
  const f32x4 v0 = *(const f32x4*)(emb + (size_t)t * 64 + i * 8);
  const f32x4 v1 = *(const f32x4*)(emb + (size_t)t * 64 + i * 8 + 4);
  s8v o;
#pragma unroll
  for (int e = 0; e < 4; ++e) { o[e] = (short)f2b(v0[e]); o[4 + e] = (short)f2b(v1[e]); }
  *(s8v*)(x1 + (size_t)row * 64 + i * 8) = o;
}

// Wxt[dir][n][k] = bf16(Wx2[dir][k][n])
__global__ void __launch_bounds__(256)
k_wxt(const float* __restrict__ Wf, const float* __restrict__ Wb,
      unsigned short* __restrict__ out)
{
  __shared__ float t[64][65];
  const int tid = threadIdx.x;
  const int kt = blockIdx.x, nt = blockIdx.y, dir = blockIdx.z;
  const float* W = dir ? Wb : Wf;
#pragma unroll
  for (int i = 0; i < 16; ++i) {
    const int c = i * 256 + tid;
    const int k = c >> 6, n = c & 63;
    t[k][n] = W[(size_t)(kt * 64 + k) * 2048 + nt * 64 + n];
  }
  __syncthreads();
#pragma unroll
  for (int i = 0; i < 16; ++i) {
    const int c = i * 256 + tid;
    const int n = c >> 6, k = c & 63;
    out[(size_t)dir * 2048 * 1024 + (size_t)(nt * 64 + n) * 1024 + kt * 64 + k] = f2b(t[k][n]);
  }
}

// Key inverse norms
__global__ void __launch_bounds__(256)
k_norms(const float* __restrict__ formE, const float* __restrict__ concK,
        const float* __restrict__ stM, const float* __restrict__ ltM,
        const float* __restrict__ infM, float* __restrict__ inn)
{
  const int i = blockIdx.x * 256 + threadIdx.x;
  if (i >= 12600) return;
  const float* src; int loc;
  if (i < 1000)       { src = formE; loc = i; }
  else if (i < 2000)  { src = concK; loc = i - 1000; }
  else if (i < 2100)  { src = stM;   loc = i - 2000; }
  else if (i < 12100) { src = ltM;   loc = i - 2100; }
  else                { src = infM;  loc = i - 12100; }
  float ss = 0.f;
#pragma unroll 16
  for (int d = 0; d < 64; ++d) { const float v = src[(size_t)loc * 64 + d]; ss += v * v; }
  inn[i] = 1.f / (sqrtf(ss) + 1e-6f);
}

// ---------------------------------------------------------------------------
// Persistent BiLSTM phase kernel.
// 64 blocks = 2 dirs x 32 WGs; each WG owns 16 h-dims (64 gate cols).
// Wh B-fragments in registers (k-split across 2 waves); h exchanged via a
// global double-buffer with device-scope atomics + per-WG flags.
// ---------------------------------------------------------------------------
template<int PHASE>
__global__ void __launch_bounds__(128, 1)
k_lstm(const unsigned short* __restrict__ xin,
       const unsigned short* __restrict__ z2fp, const unsigned short* __restrict__ z2bp,
       const float* __restrict__ Whf, const float* __restrict__ Whb,
       const float* __restrict__ Wxf, const float* __restrict__ Wxb,
       const float* __restrict__ bsf, const float* __restrict__ bsb,
       unsigned short* __restrict__ hbuf,      // [dir][parity][64][512] bf16
       unsigned short* __restrict__ yout,      // P1: y1; P2: x2
       int* __restrict__ flags,                // [dir][32]
       float* __restrict__ cg,                 // [dir][64][512] f32 (phase 2)
       int s0, int s1, int CT)
{
  __shared__ unsigned short h_lds[64 * 512];   // 64KB, XOR-swizzled
  __shared__ unsigned short x_lds[64 * 64];    // 8KB  (phase 1)
  __shared__ float g_lds[2][64 * 64];          // 32KB
  __shared__ float c_lds[64 * 16];             // 4KB
  __shared__ float bias_lds[64];

  const int tid  = threadIdx.x;
  const int wv   = tid >> 6;
  const int lane = tid & 63;
  const int wg   = blockIdx.x & 31;
  const int dir  = blockIdx.x >> 5;
  const int j0   = wg * 16;
  const int fc   = lane & 15;
  const int fk   = (lane >> 4) << 3;

  const float* Wh = dir ? Whb : Whf;
  const float* Wx = dir ? Wxb : Wxf;
  const unsigned short* Z2 = dir ? z2bp : z2fp;
  const float* BS = dir ? bsb : bsf;
  int* flg = flags + dir * 32;
  unsigned short* hb = hbuf + (size_t)dir * (2 * 64 * 512);

  for (int i = tid; i < 64; i += 128) bias_lds[i] = BS[(i >> 4) * 512 + j0 + (i & 15)];
  if (PHASE == 1 || s0 == 0) {
    for (int i = tid; i < 1024; i += 128) c_lds[i] = 0.f;
  } else {
    for (int i = tid; i < 1024; i += 128)
      c_lds[i] = cg[(size_t)dir * 64 * 512 + (i >> 4) * 512 + j0 + (i & 15)];
  }

  s8v Bh[4][8];
#pragma unroll
  for (int nt = 0; nt < 4; ++nt) {
    const int col = nt * 512 + j0 + fc;
#pragma unroll
    for (int kk = 0; kk < 8; ++kk) {
      const int kb = wv * 256 + kk * 32 + fk;
      s8v f;
#pragma unroll
      for (int i = 0; i < 8; ++i) f[i] = (short)f2b(Wh[(size_t)(kb + i) * 2048 + col]);
      Bh[nt][kk] = f;
    }
  }
  s8v Bx[4];
  if (PHASE == 1) {
#pragma unroll
    for (int nt = 0; nt < 4; ++nt) {
      const int col = nt * 512 + j0 + fc;
      const int kb = wv * 32 + fk;
      s8v f;
#pragma unroll
      for (int i = 0; i < 8; ++i) f[i] = (short)f2b(Wx[(size_t)(kb + i) * 2048 + col]);
      Bx[nt] = f;
    }
  }
  __syncthreads();

  for (int s = s0; s < s1; ++s) {
    const int t = dir ? (511 - s) : s;

    s8v zreg[4];
    if (PHASE == 1) {
#pragma unroll
      for (int i = 0; i < 4; ++i) {
        const int c = i * 128 + tid;
        const int row = c >> 3, kb = c & 7;
        s8v v = *(const s8v*)(xin + ((size_t)row * 512 + t) * 64 + kb * 8);
        *(s8v*)((char*)x_lds + row * 128 + ((kb * 16) ^ ((row & 7) << 4))) = v;
      }
    } else {
      const int gb = tid >> 1, jh = tid & 1;
      const int lt = dir ? (s1 - 1 - s) : (s - s0);
#pragma unroll
      for (int g = 0; g < 4; ++g)
        zreg[g] = *(const s8v*)(Z2 + ((size_t)(gb * CT + lt)) * 2048 + g * 512 + j0 + jh * 8);
    }

    if (s > 0) {
      const int target = s;
      int spins = 0;
      for (;;) {
        int v = (lane < 32) ? AT_LOAD(&flg[lane]) : target;
        if (__all(v >= target)) break;
        if (++spins > (1 << 18)) break;      // bounded: never hang the harness
        __builtin_amdgcn_s_sleep(2);
      }
      __threadfence();   // acquire
      const unsigned long long* hs8 =
        (const unsigned long long*)(hb + (size_t)((s - 1) & 1) * (64 * 512));
#pragma unroll 4
      for (int i = 0; i < 64; ++i) {
        const int c = i * 128 + tid;
        const int row = c >> 7, kb4 = c & 127;
        unsigned long long u = AT_LOADU(hs8 + c);
        *(unsigned long long*)((char*)h_lds + row * 1024 + ((kb4 * 8) ^ ((row & 7) << 4))) = u;
      }
    }
    __syncthreads();   // A

    f32x4 acc[4][4];
#pragma unroll
    for (int mt = 0; mt < 4; ++mt)
#pragma unroll
      for (int nt = 0; nt < 4; ++nt) acc[mt][nt] = (f32x4){0.f, 0.f, 0.f, 0.f};

    if (PHASE == 1) {
      const int kx2 = (wv * 32 + fk) * 2;
#pragma unroll
      for (int mt = 0; mt < 4; ++mt) {
        const int row = mt * 16 + fc;
        s8v a = *(const s8v*)((char*)x_lds + row * 128 + (kx2 ^ ((row & 7) << 4)));
#pragma unroll
        for (int nt = 0; nt < 4; ++nt)
          acc[mt][nt] = __builtin_amdgcn_mfma_f32_16x16x32_bf16(a, Bx[nt], acc[mt][nt], 0, 0, 0);
      }
    }
    if (s > 0) {
#pragma unroll
      for (int kk = 0; kk < 8; ++kk) {
        const int k2 = (wv * 256 + kk * 32 + fk) * 2;
        s8v a[4];
#pragma unroll
        for (int mt = 0; mt < 4; ++mt) {
          const int row = mt * 16 + fc;
          a[mt] = *(const s8v*)((char*)h_lds + row * 1024 + (k2 ^ ((row & 7) << 4)));
        }
#pragma unroll
        for (int mt = 0; mt < 4; ++mt)
#pragma unroll
          for (int nt = 0; nt < 4; ++nt)
            acc[mt][nt] = __builtin_amdgcn_mfma_f32_16x16x32_bf16(a[mt], Bh[nt][kk], acc[mt][nt], 0, 0, 0);
      }
    }
    {
      const int r0 = (lane >> 4) << 2;
#pragma unroll
      for (int mt = 0; mt < 4; ++mt)
#pragma unroll
        for (int nt = 0; nt < 4; ++nt) {
          const int colj = nt * 16 + fc;
          const int row0 = mt * 16 + r0;
#pragma unroll
          for (int r = 0; r < 4; ++r)
            g_lds[wv][(row0 + r) * 64 + colj] = acc[mt][nt][r];
        }
    }
    __syncthreads();   // B

    {
      const int gb = tid >> 1, jh = tid & 1;
      const float* g0 = g_lds[0] + gb * 64;
      const float* g1 = g_lds[1] + gb * 64;
      s8v hv;
#pragma unroll
      for (int jj = 0; jj < 8; ++jj) {
        const int j = jh * 8 + jj;
        float pi = g0[0 * 16 + j] + g1[0 * 16 + j] + bias_lds[0 * 16 + j];
        float pf = g0[1 * 16 + j] + g1[1 * 16 + j] + bias_lds[1 * 16 + j];
        float pg = g0[2 * 16 + j] + g1[2 * 16 + j] + bias_lds[2 * 16 + j];
        float po = g0[3 * 16 + j] + g1[3 * 16 + j] + bias_lds[3 * 16 + j];
        if (PHASE == 2) {
          pi += b2f((unsigned short)zreg[0][jj]);
          pf += b2f((unsigned short)zreg[1][jj]);
          pg += b2f((unsigned short)zreg[2][jj]);
          po += b2f((unsigned short)zreg[3][jj]);
        }
        const int ci = gb * 16 + j;
        const float c = sigm(pf) * c_lds[ci] + sigm(pi) * tanh_(pg);
        c_lds[ci] = c;
        hv[jj] = (short)f2b(sigm(po) * tanh_(c));
      }
      union { s8v v; unsigned long long u[2]; } cv; cv.v = hv;
      unsigned long long* dst = (unsigned long long*)
        (hb + (size_t)(s & 1) * (64 * 512) + gb * 512 + j0 + jh * 8);
      AT_STOREU(dst, cv.u[0]);
      AT_STOREU(dst + 1, cv.u[1]);
      if (PHASE == 1) {
        *(s8v*)(yout + ((size_t)gb * 512 + t) * 1024 + dir * 512 + j0 + jh * 8) = hv;
      } else if (s == 511) {
        *(s8v*)(yout + (size_t)gb * 1024 + dir * 512 + j0 + jh * 8) = hv;
      }
    }
    if (PHASE == 2 && s == s1 - 1 && s1 < 512) {
      __syncthreads();
      for (int i = tid; i < 1024; i += 128)
        cg[(size_t)dir * 64 * 512 + (i >> 4) * 512 + j0 + (i & 15)] = c_lds[i];
    }
    __threadfence();     // release (all threads)
    __syncthreads();     // C
    if (tid == 0) AT_STORE(&flg[wg], s + 1);
  }
}

// ---------------------------------------------------------------------------
// z2 chunk GEMM: (64*CT) x 2048, K=1024, 128x128 tiles
// ---------------------------------------------------------------------------
__global__ void __launch_bounds__(256)
k_zgemm(const unsigned short* __restrict__ A, const unsigned short* __restrict__ Wxt,
        unsigned short* __restrict__ Cf, unsigned short* __restrict__ Cb,
        int tb0, int tb1, int CT)
{
  __shared__ unsigned short As[128 * 64];
  __shared__ unsigned short Bs[128 * 64];
  const int tid = threadIdx.x;
  const int lane = tid & 63;
  const int w = tid >> 6;
  const int wm = w >> 1, wn = w & 1;
  const int bx = blockIdx.x, by = blockIdx.y, dz = blockIdx.z;
  const unsigned short* Bmat = Wxt + (size_t)dz * 2048 * 1024;
  unsigned short* C = dz ? Cb : Cf;
  const int tb = dz ? tb1 : tb0;
  const int fc = lane & 15, fk = (lane >> 4) << 3;

  f32x4 acc[4][4];
#pragma unroll
  for (int mt = 0; mt < 4; ++mt)
#pragma unroll
    for (int nt = 0; nt < 4; ++nt) acc[mt][nt] = (f32x4){0.f, 0.f, 0.f, 0.f};

  for (int kt = 0; kt < 16; ++kt) {
    __syncthreads();
#pragma unroll
    for (int i = 0; i < 4; ++i) {
      const int c = i * 256 + tid;
      const int row = c >> 3, kb = c & 7;
      const int m = by * 128 + row;
      const int b = m / CT, lt = m - b * CT;
      s8v v = *(const s8v*)(A + ((size_t)b * 512 + tb + lt) * 1024 + kt * 64 + kb * 8);
      *(s8v*)((char*)As + row * 128 + ((kb * 16) ^ ((row & 7) << 4))) = v;
    }
#pragma unroll
    for (int i = 0; i < 4; ++i) {
      const int c = i * 256 + tid;
      const int n = c >> 3, kb = c & 7;
      s8v v = *(const s8v*)(Bmat + (size_t)(bx * 128 + n) * 1024 + kt * 64 + kb * 8);
      *(s8v*)((char*)Bs + n * 128 + ((kb * 16) ^ ((n & 7) << 4))) = v;
    }
    __syncthreads();
#pragma unroll
    for (int kk = 0; kk < 2; ++kk) {
      const int k2 = (kk * 32 + fk) * 2;
      s8v a[4], bfr[4];
#pragma unroll
      for (int mt = 0; mt < 4; ++mt) {
        const int row = wm * 64 + mt * 16 + fc;
        a[mt] = *(const s8v*)((char*)As + row * 128 + (k2 ^ ((row & 7) << 4)));
      }
#pragma unroll
      for (int nt = 0; nt < 4; ++nt) {
        const int n = wn * 64 + nt * 16 + fc;
        bfr[nt] = *(const s8v*)((char*)Bs + n * 128 + (k2 ^ ((n & 7) << 4)));
      }
#pragma unroll
      for (int mt = 0; mt < 4; ++mt)
#pragma unroll
        for (int nt = 0; nt < 4; ++nt)
          acc[mt][nt] = __builtin_amdgcn_mfma_f32_16x16x32_bf16(a[mt], bfr[nt], acc[mt][nt], 0, 0, 0);
    }
  }
  const int r0 = (lane >> 4) << 2;
#pragma unroll
  for (int mt = 0; mt < 4; ++mt)
#pragma unroll
    for (int nt = 0; nt < 4; ++nt) {
      const size_t rowg = (size_t)(by * 128 + wm * 64 + mt * 16 + r0);
      const int colg = bx * 128 + wn * 64 + nt * 16 + fc;
#pragma unroll
      for (int r = 0; r < 4; ++r)
        C[(rowg + r) * 2048 + colg] = f2b(acc[mt][nt][r]);
    }
}

// ---------------------------------------------------------------------------
// Head part 1: S=1 attention collapses to v-proj -> Wo -> query
// ---------------------------------------------------------------------------
__global__ void __launch_bounds__(256)
k_head1(const unsigned short* __restrict__ x2,
        const float* __restrict__ Wv, const float* __restrict__ bv,
        const float* __restrict__ Wo, const float* __restrict__ bo,
        const float* __restrict__ mqW, const float* __restrict__ mqb,
        float* __restrict__ query)
{
  __shared__ float xs[1024], ys[512], x3[1024];
  __shared__ float part[4][64];
  const int b = blockIdx.x, tid = threadIdx.x;
  for (int i = tid; i < 1024; i += 256) xs[i] = b2f(x2[(size_t)b * 1024 + i]);
  __syncthreads();
  {
    const int o = tid * 2;
    float a0 = 0.f, a1 = 0.f;
#pragma unroll 8
    for (int e = 0; e < 1024; ++e) {
      const float xv = xs[e];
      a0 += xv * Wv[(size_t)e * 512 + o];
      a1 += xv * Wv[(size_t)e * 512 + o + 1];
    }
    ys[o] = a0 + bv[o];
    ys[o + 1] = a1 + bv[o + 1];
  }
  __syncthreads();
  {
    const int e0 = tid * 4;
    float a0 = 0.f, a1 = 0.f, a2 = 0.f, a3 = 0.f;
#pragma unroll 8
    for (int h = 0; h < 512; ++h) {
      const float yv = ys[h];
      a0 += yv * Wo[(size_t)h * 1024 + e0];
      a1 += yv * Wo[(size_t)h * 1024 + e0 + 1];
      a2 += yv * Wo[(size_t)h * 1024 + e0 + 2];
      a3 += yv * Wo[(size_t)h * 1024 + e0 + 3];
    }
    x3[e0] = a0 + bo[e0];
    x3[e0 + 1] = a1 + bo[e0 + 1];
    x3[e0 + 2] = a2 + bo[e0 + 2];
    x3[e0 + 3] = a3 + bo[e0 + 3];
  }
  __syncthreads();
  {
    const int o = tid & 63, kc = tid >> 6;
    float a = 0.f;
#pragma unroll 8
    for (int e = kc * 256; e < kc * 256 + 256; ++e) a += x3[e] * mqW[(size_t)e * 64 + o];
    part[kc][o] = a;
  }
  __syncthreads();
  if (tid < 64)
    query[b * 64 + tid] = part[0][tid] + part[1][tid] + part[2][tid] + part[3][tid] + mqb[tid];
}

// ---------------------------------------------------------------------------
// Head part 2: memory retrievals + MLP + sigmoid (f32 output!)
// ---------------------------------------------------------------------------
__device__ void bank_topk(const float* __restrict__ K, const float* __restrict__ V,
                          int n, const float* __restrict__ W, const float* __restrict__ inn,
                          float qinv, const float* q, float* sims, float* red, int* redi,
                          float* acc64, int tid)
{
  for (int i = tid; i < n; i += 256) {
    float s = 0.f;
#pragma unroll 16
    for (int d = 0; d < 64; ++d) s += q[d] * K[(size_t)i * 64 + d];
    s *= qinv * inn[i];
    if (W) s *= W[i];
    sims[i] = s;
  }
  __syncthreads();
  for (int it = 0; it < 5; ++it) {
    float bv = -1e30f; int bi = 1 << 30;
    for (int i = tid; i < n; i += 256) {
      const float v = sims[i];
      if (v > bv) { bv = v; bi = i; }
    }
    red[tid] = bv; redi[tid] = bi;
    __syncthreads();
    for (int st = 128; st >= 1; st >>= 1) {
      if (tid < st) {
        const float v = red[tid + st]; const int ix = redi[tid + st];
        if (v > red[tid] || (v == red[tid] && ix < redi[tid])) { red[tid] = v; redi[tid] = ix; }
      }
      __syncthreads();
    }
    const int sel = redi[0];
    if (tid < 64) acc64[tid] += V[(size_t)sel * 64 + tid];
    if (tid == 0) sims[sel] = -1e30f;
    __syncthreads();
  }
}

__global__ void __launch_bounds__(256)
k_head2(const float* __restrict__ query,
        const float* extK, const float* extV,
        const float* formE, const float* concK, const float* concV,
        const float* stM, const float* ltM, const float* ltW,
        const float* infM, const float* infW,
        const float* __restrict__ inn,
        const float* rsW, const float* rsb,
        const float* gma, const float* bta,
        const float* mea, const float* vr,
        const float* outW, const float* outb,
        const float* finW, const float* finb,
        float* __restrict__ out)
{
  __shared__ float q[64];
  __shared__ float acc64[64];
  __shared__ float sims[10000];
  __shared__ float red[256];
  __shared__ int redi[256];
  __shared__ float r1[512];
  __shared__ float o2[128];

  const int b = blockIdx.x, tid = threadIdx.x;
  if (tid < 64) q[tid] = query[b * 64 + tid];
  __syncthreads();
  red[tid] = (tid < 64) ? q[tid] * q[tid] : 0.f;
  __syncthreads();
  for (int st = 128; st >= 1; st >>= 1) { if (tid < st) red[tid] += red[tid + st]; __syncthreads(); }
  const float qinv = 1.f / (sqrtf(red[0]) + 1e-6f);
  __syncthreads();

  if (tid < 100) {
    float s = 0.f;
#pragma unroll 16
    for (int d = 0; d < 64; ++d) s += q[d] * extK[(size_t)tid * 64 + d];
    sims[tid] = s;
  }
  __syncthreads();
  red[tid] = (tid < 100) ? sims[tid] : -1e30f;
  __syncthreads();
  for (int st = 128; st >= 1; st >>= 1) { if (tid < st && red[tid + st] > red[tid]) red[tid] = red[tid + st]; __syncthreads(); }
  const float mx = red[0];
  __syncthreads();
  red[tid] = (tid < 100) ? __expf(sims[tid] - mx) : 0.f;
  __syncthreads();
  for (int st = 128; st >= 1; st >>= 1) { if (tid < st) red[tid] += red[tid + st]; __syncthreads(); }
  const float Z = red[0];
  __syncthreads();
  if (tid < 100) sims[tid] = __expf(sims[tid] - mx) / Z;
  __syncthreads();
  if (tid < 64) {
    float a = 0.f;
    for (int i = 0; i < 100; ++i) a += sims[i] * extV[(size_t)i * 64 + tid];
    acc64[tid] = a;
  }
  __syncthreads();

  bank_topk(formE, formE, 1000,  nullptr, inn + 0,     qinv, q, sims, red, redi, acc64, tid);
  bank_topk(concK, concV, 1000,  nullptr, inn + 1000,  qinv, q, sims, red, redi, acc64, tid);
  bank_topk(stM,   stM,   100,   nullptr, inn + 2000,  qinv, q, sims, red, redi, acc64, tid);
  bank_topk(ltM,   ltM,   10000, ltW,     inn + 2100,  qinv, q, sims, red, redi, acc64, tid);
  bank_topk(infM,  infM,  500,   infW,    inn + 12100, qinv, q, sims, red, redi, acc64, tid);

  if (tid < 64) acc64[tid] *= (1.f / 26.f);
  __syncthreads();

  {
    const int o = tid * 2;
    float a0 = 0.f, a1 = 0.f;
#pragma unroll 16
    for (int d = 0; d < 64; ++d) {
      const float xv = acc64[d];
      a0 += xv * rsW[(size_t)d * 512 + o];
      a1 += xv * rsW[(size_t)d * 512 + o + 1];
    }
    a0 = fmaxf(a0 + rsb[o], 0.f);
    a1 = fmaxf(a1 + rsb[o + 1], 0.f);
    r1[o]     = (a0 - mea[o])     / sqrtf(vr[o]     + 1e-3f) * gma[o]     + bta[o];
    r1[o + 1] = (a1 - mea[o + 1]) / sqrtf(vr[o + 1] + 1e-3f) * gma[o + 1] + bta[o + 1];
  }
  __syncthreads();
  if (tid < 128) {
    float a = 0.f;
#pragma unroll 8
    for (int j = 0; j < 512; ++j) a += r1[j] * outW[(size_t)j * 128 + tid];
    o2[tid] = a + outb[tid];
  }
  __syncthreads();
  red[tid] = (tid < 128) ? o2[tid] * finW[tid] : 0.f;
  __syncthreads();
  for (int st = 128; st >= 1; st >>= 1) { if (tid < st) red[tid] += red[tid + st]; __syncthreads(); }
  if (tid == 0) out[b] = sigm(red[0] + finb[0]);   // FLOAT32 output
}

// Diagnostic: encode ws MiB as float
__global__ void k_diag(float* out, int n, float val) {
  const int i = blockIdx.x * 64 + threadIdx.x;
  if (i < n) out[i] = val;
}

// ---------------------------------------------------------------------------
// Launch
// ---------------------------------------------------------------------------
extern "C" void kernel_launch(void* const* d_in, const int* in_sizes, int n_in,
                              void* d_out, int out_size, void* d_ws, size_t ws_size,
                              hipStream_t stream)
{
  (void)in_sizes; (void)n_in;
  const int*   tokens = (const int*)d_in[0];
  const float* emb    = (const float*)d_in[1];
  const float* l1fWx  = (const float*)d_in[2];
  const float* l1fWh  = (const float*)d_in[3];
  const float* l1fb   = (const float*)d_in[4];
  const float* l1bWx  = (const float*)d_in[5];
  const float* l1bWh  = (const float*)d_in[6];
  const float* l1bb   = (const float*)d_in[7];
  const float* l2fWx  = (const float*)d_in[8];
  const float* l2fWh  = (const float*)d_in[9];
  const float* l2fb   = (const float*)d_in[10];
  const float* l2bWx  = (const float*)d_in[11];
  const float* l2bWh  = (const float*)d_in[12];
  const float* l2bb   = (const float*)d_in[13];
  const float* Wv     = (const float*)d_in[18];
  const float* bv     = (const float*)d_in[19];
  const float* Wo     = (const float*)d_in[20];
  const float* bo     = (const float*)d_in[21];
  const float* mqW    = (const float*)d_in[22];
  const float* mqb    = (const float*)d_in[23];
  const float* extK   = (const float*)d_in[24];
  const float* extV   = (const float*)d_in[25];
  const float* formE  = (const float*)d_in[26];
  const float* concK  = (const float*)d_in[27];
  const float* concV  = (const float*)d_in[28];
  const float* stM    = (const float*)d_in[29];
  const float* ltM    = (const float*)d_in[30];
  const float* ltW    = (const float*)d_in[31];
  const float* infM   = (const float*)d_in[32];
  const float* infW   = (const float*)d_in[33];
  const float* rsW    = (const float*)d_in[34];
  const float* rsb    = (const float*)d_in[35];
  const float* gma    = (const float*)d_in[36];
  const float* bta    = (const float*)d_in[37];
  const float* mea    = (const float*)d_in[38];
  const float* vr     = (const float*)d_in[39];
  const float* outW   = (const float*)d_in[40];
  const float* outb   = (const float*)d_in[41];
  const float* finW   = (const float*)d_in[42];
  const float* finb   = (const float*)d_in[43];

  float* outp = (float*)d_out;   // reference output dtype is FLOAT32
  char* ws = (char*)d_ws;

  size_t off = 0;
  auto take = [&](size_t sz) { size_t o = off; off += (sz + 255) & ~(size_t)255; return o; };
  const size_t o_x1    = take((size_t)64 * 512 * 64 * 2);
  const size_t o_y1    = take((size_t)64 * 512 * 1024 * 2);
  const size_t o_wxt   = take((size_t)2 * 2048 * 1024 * 2);
  const size_t o_h1    = take((size_t)2 * 2 * 64 * 512 * 2);
  const size_t o_h2    = take((size_t)2 * 2 * 64 * 512 * 2);
  const size_t o_cg    = take((size_t)2 * 64 * 512 * 4);
  const size_t o_x2    = take((size_t)64 * 1024 * 2);
  const size_t o_query = take((size_t)64 * 64 * 4);
  const size_t o_norms = take((size_t)12600 * 4);
  const size_t o_flags = take(512);
  const size_t base = off;

  int CT = 0;
  const int cts[6] = {512, 256, 128, 64, 32, 16};
  for (int i = 0; i < 6; ++i) {
    const size_t need = base + (size_t)cts[i] * 524288 + 256;
    if (need <= ws_size) { CT = cts[i]; break; }
  }
  if (CT == 0) {
    k_diag<<<1, 64, 0, stream>>>(outp, out_size, (float)(ws_size >> 20));
    return;
  }
  const size_t o_zc = take((size_t)CT * 524288);

  unsigned short* x1   = (unsigned short*)(ws + o_x1);
  unsigned short* y1   = (unsigned short*)(ws + o_y1);
  unsigned short* wxt  = (unsigned short*)(ws + o_wxt);
  unsigned short* h1   = (unsigned short*)(ws + o_h1);
  unsigned short* h2   = (unsigned short*)(ws + o_h2);
  float*          cg   = (float*)(ws + o_cg);
  unsigned short* x2   = (unsigned short*)(ws + o_x2);
  float*          qry  = (float*)(ws + o_query);
  float*          nrm  = (float*)(ws + o_norms);
  int*            flags = (int*)(ws + o_flags);
  unsigned short* zcf  = (unsigned short*)(ws + o_zc);
  unsigned short* zcb  = zcf + (size_t)64 * CT * 2048;

  hipMemsetAsync(flags, 0, 512, stream);
  k_embed<<<1024, 256, 0, stream>>>(tokens, emb, x1);
  k_norms<<<50, 256, 0, stream>>>(formE, concK, stM, ltM, infM, nrm);
  k_wxt<<<dim3(16, 32, 2), 256, 0, stream>>>(l2fWx, l2bWx, wxt);

  k_lstm<1><<<64, 128, 0, stream>>>(x1, nullptr, nullptr, l1fWh, l1bWh, l1fWx, l1bWx,
                                    l1fb, l1bb, h1, y1, flags, nullptr, 0, 512, 512);

  const int nC = 512 / CT;
  for (int c = 0; c < nC; ++c) {
    const int s0 = c * CT, s1 = s0 + CT;
    k_zgemm<<<dim3(16, (64 * CT) / 128, 2), 256, 0, stream>>>(
        y1, wxt, zcf, zcb, s0, 512 - s1, CT);
    k_lstm<2><<<64, 128, 0, stream>>>(nullptr, zcf, zcb, l2fWh, l2bWh, nullptr, nullptr,
                                      l2fb, l2bb, h2, x2, flags + 64, cg, s0, s1, CT);
  }

  k_head1<<<64, 256, 0, stream>>>(x2, Wv, bv, Wo, bo, mqW, mqb, qry);
  k_head2<<<64, 256, 0, stream>>>(qry, extK, extV, formE, concK, concV, stM, ltM, ltW,
                                  infM, infW, nrm, rsW, rsb, gma, bta, mea, vr,
                                  outW, outb, finW, finb, outp);
}

// Round 7
// 20253.351 us; speedup vs baseline: 1.2984x; 1.2984x over previous
//
#include <hip/hip_runtime.h>
#include <cstddef>
#include <cstdint>

typedef short s8v   __attribute__((ext_vector_type(8)));   // 8 x bf16 bits
typedef float f32x4 __attribute__((ext_vector_type(4)));

__device__ __forceinline__ float b2f(unsigned short u) {
  union { unsigned u; float f; } x; x.u = ((unsigned)u) << 16; return x.f;
}
__device__ __forceinline__ unsigned short f2b(float f) {
  union { float f; unsigned u; } x; x.f = f;
  unsigned u = x.u;
  return (unsigned short)((u + 0x7FFFu + ((u >> 16) & 1u)) >> 16);  // RNE
}
__device__ __forceinline__ float sigm(float x) { return 1.f / (1.f + __expf(-x)); }
__device__ __forceinline__ float tanh_(float x) { return 1.f - 2.f / (__expf(2.f * x) + 1.f); }

#define AT_LOAD(p)     __hip_atomic_load((p), __ATOMIC_RELAXED, __HIP_MEMORY_SCOPE_AGENT)
#define AT_STORE(p,v)  __hip_atomic_store((p), (v), __ATOMIC_RELEASE, __HIP_MEMORY_SCOPE_AGENT)

// ---------------------------------------------------------------------------
// Embedding gather + f32->bf16
// ---------------------------------------------------------------------------
__global__ void __launch_bounds__(256)
k_embed(const int* __restrict__ tok, const float* __restrict__ emb,
        unsigned short* __restrict__ x1)
{
  const int g = blockIdx.x * 256 + threadIdx.x;
  if (g >= 64 * 512 * 8) return;
  const int row = g >> 3, i = g & 7;
  const int t = tok[row];
  const f32x4 v0 = *(const f32x4*)(emb + (size_t)t * 64 + i * 8);
  const f32x4 v1 = *(const f32x4*)(emb + (size_t)t * 64 + i * 8 + 4);
  s8v o;
#pragma unroll
  for (int e = 0; e < 4; ++e) { o[e] = (short)f2b(v0[e]); o[4 + e] = (short)f2b(v1[e]); }
  *(s8v*)(x1 + (size_t)row * 64 + i * 8) = o;
}

// Wxt[dir][n][k] = bf16(Wx2[dir][k][n])
__global__ void __launch_bounds__(256)
k_wxt(const float* __restrict__ Wf, const float* __restrict__ Wb,
      unsigned short* __restrict__ out)
{
  __shared__ float t[64][65];
  const int tid = threadIdx.x;
  const int kt = blockIdx.x, nt = blockIdx.y, dir = blockIdx.z;
  const float* W = dir ? Wb : Wf;
#pragma unroll
  for (int i = 0; i < 16; ++i) {
    const int c = i * 256 + tid;
    const int k = c >> 6, n = c & 63;
    t[k][n] = W[(size_t)(kt * 64 + k) * 2048 + nt * 64 + n];
  }
  __syncthreads();
#pragma unroll
  for (int i = 0; i < 16; ++i) {
    const int c = i * 256 + tid;
    const int n = c >> 6, k = c & 63;
    out[(size_t)dir * 2048 * 1024 + (size_t)(nt * 64 + n) * 1024 + kt * 64 + k] = f2b(t[k][n]);
  }
}

// Key inverse norms
__global__ void __launch_bounds__(256)
k_norms(const float* __restrict__ formE, const float* __restrict__ concK,
        const float* __restrict__ stM, const float* __restrict__ ltM,
        const float* __restrict__ infM, float* __restrict__ inn)
{
  const int i = blockIdx.x * 256 + threadIdx.x;
  if (i >= 12600) return;
  const float* src; int loc;
  if (i < 1000)       { src = formE; loc = i; }
  else if (i < 2000)  { src = concK; loc = i - 1000; }
  else if (i < 2100)  { src = stM;   loc = i - 2000; }
  else if (i < 12100) { src = ltM;   loc = i - 2100; }
  else                { src = infM;  loc = i - 12100; }
  float ss = 0.f;
#pragma unroll 16
  for (int d = 0; d < 64; ++d) { const float v = src[(size_t)loc * 64 + d]; ss += v * v; }
  inn[i] = 1.f / (sqrtf(ss) + 1e-6f);
}

// ---------------------------------------------------------------------------
// Persistent BiLSTM phase kernel.
// 64 blocks = 2 dirs x 32 WGs; each WG owns 16 h-dims (64 gate cols).
// Wh B-fragments in registers; h exchanged via global double-buffer:
// plain 16B vector stores/loads (L2/L3-served), flags via device atomics,
// release = all-thread threadfence before barrier, acquire = threadfence
// after flag spin (invalidates vL1).  [r2==r4 bit-identical => safe]
// ---------------------------------------------------------------------------
template<int PHASE>
__global__ void __launch_bounds__(128, 1)
k_lstm(const unsigned short* __restrict__ xin,
       const unsigned short* __restrict__ z2fp, const unsigned short* __restrict__ z2bp,
       const float* __restrict__ Whf, const float* __restrict__ Whb,
       const float* __restrict__ Wxf, const float* __restrict__ Wxb,
       const float* __restrict__ bsf, const float* __restrict__ bsb,
       unsigned short* __restrict__ hbuf,      // [dir][parity][64][512] bf16
       unsigned short* __restrict__ yout,      // P1: y1; P2: x2
       int* __restrict__ flags,                // [dir][32]
       float* __restrict__ cg,                 // [dir][64][512] f32 (phase 2)
       int s0, int s1, int CT)
{
  __shared__ unsigned short h_lds[64 * 512];   // 64KB, XOR-swizzled
  __shared__ unsigned short x_lds[64 * 64];    // 8KB  (phase 1)
  __shared__ float g_lds[2][64 * 64];          // 32KB
  __shared__ float c_lds[64 * 16];             // 4KB
  __shared__ float bias_lds[64];

  const int tid  = threadIdx.x;
  const int wv   = tid >> 6;
  const int lane = tid & 63;
  const int wg   = blockIdx.x & 31;
  const int dir  = blockIdx.x >> 5;
  const int j0   = wg * 16;
  const int fc   = lane & 15;
  const int fk   = (lane >> 4) << 3;

  const float* Wh = dir ? Whb : Whf;
  const float* Wx = dir ? Wxb : Wxf;
  const unsigned short* Z2 = dir ? z2bp : z2fp;
  const float* BS = dir ? bsb : bsf;
  int* flg = flags + dir * 32;
  unsigned short* hb = hbuf + (size_t)dir * (2 * 64 * 512);

  for (int i = tid; i < 64; i += 128) bias_lds[i] = BS[(i >> 4) * 512 + j0 + (i & 15)];
  if (PHASE == 1 || s0 == 0) {
    for (int i = tid; i < 1024; i += 128) c_lds[i] = 0.f;
  } else {
    for (int i = tid; i < 1024; i += 128)
      c_lds[i] = cg[(size_t)dir * 64 * 512 + (i >> 4) * 512 + j0 + (i & 15)];
  }

  s8v Bh[4][8];
#pragma unroll
  for (int nt = 0; nt < 4; ++nt) {
    const int col = nt * 512 + j0 + fc;
#pragma unroll
    for (int kk = 0; kk < 8; ++kk) {
      const int kb = wv * 256 + kk * 32 + fk;
      s8v f;
#pragma unroll
      for (int i = 0; i < 8; ++i) f[i] = (short)f2b(Wh[(size_t)(kb + i) * 2048 + col]);
      Bh[nt][kk] = f;
    }
  }
  s8v Bx[4];
  if (PHASE == 1) {
#pragma unroll
    for (int nt = 0; nt < 4; ++nt) {
      const int col = nt * 512 + j0 + fc;
      const int kb = wv * 32 + fk;
      s8v f;
#pragma unroll
      for (int i = 0; i < 8; ++i) f[i] = (short)f2b(Wx[(size_t)(kb + i) * 2048 + col]);
      Bx[nt] = f;
    }
  }
  __syncthreads();

  for (int s = s0; s < s1; ++s) {
    const int t = dir ? (511 - s) : s;

    s8v zreg[4];
    if (PHASE == 1) {
#pragma unroll
      for (int i = 0; i < 4; ++i) {
        const int c = i * 128 + tid;
        const int row = c >> 3, kb = c & 7;
        s8v v = *(const s8v*)(xin + ((size_t)row * 512 + t) * 64 + kb * 8);
        *(s8v*)((char*)x_lds + row * 128 + ((kb * 16) ^ ((row & 7) << 4))) = v;
      }
    } else {
      const int gb = tid >> 1, jh = tid & 1;
      const int lt = dir ? (s1 - 1 - s) : (s - s0);
#pragma unroll
      for (int g = 0; g < 4; ++g)
        zreg[g] = *(const s8v*)(Z2 + ((size_t)(gb * CT + lt)) * 2048 + g * 512 + j0 + jh * 8);
    }

    if (s > 0) {
      const int target = s;
      int spins = 0;
      for (;;) {
        int v = (lane < 32) ? AT_LOAD(&flg[lane]) : target;
        if (__all(v >= target)) break;
        if (++spins > (1 << 18)) break;      // bounded: never hang the harness
        __builtin_amdgcn_s_sleep(1);
      }
      __threadfence();   // acquire: invalidate vL1 so h reads are fresh
      // stage h_{s-1}: plain 16B vector loads (L2/L3-served, cacheable)
      const unsigned short* hsrc = hb + (size_t)((s - 1) & 1) * (64 * 512);
#pragma unroll 8
      for (int i = 0; i < 32; ++i) {
        const int c = i * 128 + tid;          // 4096 chunks of 16B
        const int row = c >> 6, kb = c & 63;
        s8v v = *(const s8v*)(hsrc + row * 512 + kb * 8);
        *(s8v*)((char*)h_lds + row * 1024 + ((kb * 16) ^ ((row & 7) << 4))) = v;
      }
    }
    __syncthreads();   // A

    f32x4 acc[4][4];
#pragma unroll
    for (int mt = 0; mt < 4; ++mt)
#pragma unroll
      for (int nt = 0; nt < 4; ++nt) acc[mt][nt] = (f32x4){0.f, 0.f, 0.f, 0.f};

    if (PHASE == 1) {
      const int kx2 = (wv * 32 + fk) * 2;
#pragma unroll
      for (int mt = 0; mt < 4; ++mt) {
        const int row = mt * 16 + fc;
        s8v a = *(const s8v*)((char*)x_lds + row * 128 + (kx2 ^ ((row & 7) << 4)));
#pragma unroll
        for (int nt = 0; nt < 4; ++nt)
          acc[mt][nt] = __builtin_amdgcn_mfma_f32_16x16x32_bf16(a, Bx[nt], acc[mt][nt], 0, 0, 0);
      }
    }
    if (s > 0) {
#pragma unroll
      for (int kk = 0; kk < 8; ++kk) {
        const int k2 = (wv * 256 + kk * 32 + fk) * 2;
        s8v a[4];
#pragma unroll
        for (int mt = 0; mt < 4; ++mt) {
          const int row = mt * 16 + fc;
          a[mt] = *(const s8v*)((char*)h_lds + row * 1024 + (k2 ^ ((row & 7) << 4)));
        }
#pragma unroll
        for (int mt = 0; mt < 4; ++mt)
#pragma unroll
          for (int nt = 0; nt < 4; ++nt)
            acc[mt][nt] = __builtin_amdgcn_mfma_f32_16x16x32_bf16(a[mt], Bh[nt][kk], acc[mt][nt], 0, 0, 0);
      }
    }
    {
      const int r0 = (lane >> 4) << 2;
#pragma unroll
      for (int mt = 0; mt < 4; ++mt)
#pragma unroll
        for (int nt = 0; nt < 4; ++nt) {
          const int colj = nt * 16 + fc;
          const int row0 = mt * 16 + r0;
#pragma unroll
          for (int r = 0; r < 4; ++r)
            g_lds[wv][(row0 + r) * 64 + colj] = acc[mt][nt][r];
        }
    }
    __syncthreads();   // B

    {
      const int gb = tid >> 1, jh = tid & 1;
      const float* g0 = g_lds[0] + gb * 64;
      const float* g1 = g_lds[1] + gb * 64;
      s8v hv;
#pragma unroll
      for (int jj = 0; jj < 8; ++jj) {
        const int j = jh * 8 + jj;
        float pi = g0[0 * 16 + j] + g1[0 * 16 + j] + bias_lds[0 * 16 + j];
        float pf = g0[1 * 16 + j] + g1[1 * 16 + j] + bias_lds[1 * 16 + j];
        float pg = g0[2 * 16 + j] + g1[2 * 16 + j] + bias_lds[2 * 16 + j];
        float po = g0[3 * 16 + j] + g1[3 * 16 + j] + bias_lds[3 * 16 + j];
        if (PHASE == 2) {
          pi += b2f((unsigned short)zreg[0][jj]);
          pf += b2f((unsigned short)zreg[1][jj]);
          pg += b2f((unsigned short)zreg[2][jj]);
          po += b2f((unsigned short)zreg[3][jj]);
        }
        const int ci = gb * 16 + j;
        const float c = sigm(pf) * c_lds[ci] + sigm(pi) * tanh_(pg);
        c_lds[ci] = c;
        hv[jj] = (short)f2b(sigm(po) * tanh_(c));
      }
      // publish h: plain 16B store (release via threadfence below)
      *(s8v*)(hb + (size_t)(s & 1) * (64 * 512) + gb * 512 + j0 + jh * 8) = hv;
      if (PHASE == 1) {
        *(s8v*)(yout + ((size_t)gb * 512 + t) * 1024 + dir * 512 + j0 + jh * 8) = hv;
      } else if (s == 511) {
        *(s8v*)(yout + (size_t)gb * 1024 + dir * 512 + j0 + jh * 8) = hv;
      }
    }
    if (PHASE == 2 && s == s1 - 1 && s1 < 512) {
      __syncthreads();
      for (int i = tid; i < 1024; i += 128)
        cg[(size_t)dir * 64 * 512 + (i >> 4) * 512 + j0 + (i & 15)] = c_lds[i];
    }
    __threadfence();     // release (all threads: flush h to coherent point)
    __syncthreads();     // C
    if (tid == 0) AT_STORE(&flg[wg], s + 1);
  }
}

// ---------------------------------------------------------------------------
// z2 chunk GEMM: (64*CT) x 2048, K=1024, 128x128 tiles
// ---------------------------------------------------------------------------
__global__ void __launch_bounds__(256)
k_zgemm(const unsigned short* __restrict__ A, const unsigned short* __restrict__ Wxt,
        unsigned short* __restrict__ Cf, unsigned short* __restrict__ Cb,
        int tb0, int tb1, int CT)
{
  __shared__ unsigned short As[128 * 64];
  __shared__ unsigned short Bs[128 * 64];
  const int tid = threadIdx.x;
  const int lane = tid & 63;
  const int w = tid >> 6;
  const int wm = w >> 1, wn = w & 1;
  const int bx = blockIdx.x, by = blockIdx.y, dz = blockIdx.z;
  const unsigned short* Bmat = Wxt + (size_t)dz * 2048 * 1024;
  unsigned short* C = dz ? Cb : Cf;
  const int tb = dz ? tb1 : tb0;
  const int fc = lane & 15, fk = (lane >> 4) << 3;

  f32x4 acc[4][4];
#pragma unroll
  for (int mt = 0; mt < 4; ++mt)
#pragma unroll
    for (int nt = 0; nt < 4; ++nt) acc[mt][nt] = (f32x4){0.f, 0.f, 0.f, 0.f};

  for (int kt = 0; kt < 16; ++kt) {
    __syncthreads();
#pragma unroll
    for (int i = 0; i < 4; ++i) {
      const int c = i * 256 + tid;
      const int row = c >> 3, kb = c & 7;
      const int m = by * 128 + row;
      const int b = m / CT, lt = m - b * CT;
      s8v v = *(const s8v*)(A + ((size_t)b * 512 + tb + lt) * 1024 + kt * 64 + kb * 8);
      *(s8v*)((char*)As + row * 128 + ((kb * 16) ^ ((row & 7) << 4))) = v;
    }
#pragma unroll
    for (int i = 0; i < 4; ++i) {
      const int c = i * 256 + tid;
      const int n = c >> 3, kb = c & 7;
      s8v v = *(const s8v*)(Bmat + (size_t)(bx * 128 + n) * 1024 + kt * 64 + kb * 8);
      *(s8v*)((char*)Bs + n * 128 + ((kb * 16) ^ ((n & 7) << 4))) = v;
    }
    __syncthreads();
#pragma unroll
    for (int kk = 0; kk < 2; ++kk) {
      const int k2 = (kk * 32 + fk) * 2;
      s8v a[4], bfr[4];
#pragma unroll
      for (int mt = 0; mt < 4; ++mt) {
        const int row = wm * 64 + mt * 16 + fc;
        a[mt] = *(const s8v*)((char*)As + row * 128 + (k2 ^ ((row & 7) << 4)));
      }
#pragma unroll
      for (int nt = 0; nt < 4; ++nt) {
        const int n = wn * 64 + nt * 16 + fc;
        bfr[nt] = *(const s8v*)((char*)Bs + n * 128 + (k2 ^ ((n & 7) << 4)));
      }
#pragma unroll
      for (int mt = 0; mt < 4; ++mt)
#pragma unroll
        for (int nt = 0; nt < 4; ++nt)
          acc[mt][nt] = __builtin_amdgcn_mfma_f32_16x16x32_bf16(a[mt], bfr[nt], acc[mt][nt], 0, 0, 0);
    }
  }
  const int r0 = (lane >> 4) << 2;
#pragma unroll
  for (int mt = 0; mt < 4; ++mt)
#pragma unroll
    for (int nt = 0; nt < 4; ++nt) {
      const size_t rowg = (size_t)(by * 128 + wm * 64 + mt * 16 + r0);
      const int colg = bx * 128 + wn * 64 + nt * 16 + fc;
#pragma unroll
      for (int r = 0; r < 4; ++r)
        C[(rowg + r) * 2048 + colg] = f2b(acc[mt][nt][r]);
    }
}

// ---------------------------------------------------------------------------
// Head part 1: S=1 attention collapses to v-proj -> Wo -> query
// ---------------------------------------------------------------------------
__global__ void __launch_bounds__(256)
k_head1(const unsigned short* __restrict__ x2,
        const float* __restrict__ Wv, const float* __restrict__ bv,
        const float* __restrict__ Wo, const float* __restrict__ bo,
        const float* __restrict__ mqW, const float* __restrict__ mqb,
        float* __restrict__ query)
{
  __shared__ float xs[1024], ys[512], x3[1024];
  __shared__ float part[4][64];
  const int b = blockIdx.x, tid = threadIdx.x;
  for (int i = tid; i < 1024; i += 256) xs[i] = b2f(x2[(size_t)b * 1024 + i]);
  __syncthreads();
  {
    const int o = tid * 2;
    float a0 = 0.f, a1 = 0.f;
#pragma unroll 8
    for (int e = 0; e < 1024; ++e) {
      const float xv = xs[e];
      a0 += xv * Wv[(size_t)e * 512 + o];
      a1 += xv * Wv[(size_t)e * 512 + o + 1];
    }
    ys[o] = a0 + bv[o];
    ys[o + 1] = a1 + bv[o + 1];
  }
  __syncthreads();
  {
    const int e0 = tid * 4;
    float a0 = 0.f, a1 = 0.f, a2 = 0.f, a3 = 0.f;
#pragma unroll 8
    for (int h = 0; h < 512; ++h) {
      const float yv = ys[h];
      a0 += yv * Wo[(size_t)h * 1024 + e0];
      a1 += yv * Wo[(size_t)h * 1024 + e0 + 1];
      a2 += yv * Wo[(size_t)h * 1024 + e0 + 2];
      a3 += yv * Wo[(size_t)h * 1024 + e0 + 3];
    }
    x3[e0] = a0 + bo[e0];
    x3[e0 + 1] = a1 + bo[e0 + 1];
    x3[e0 + 2] = a2 + bo[e0 + 2];
    x3[e0 + 3] = a3 + bo[e0 + 3];
  }
  __syncthreads();
  {
    const int o = tid & 63, kc = tid >> 6;
    float a = 0.f;
#pragma unroll 8
    for (int e = kc * 256; e < kc * 256 + 256; ++e) a += x3[e] * mqW[(size_t)e * 64 + o];
    part[kc][o] = a;
  }
  __syncthreads();
  if (tid < 64)
    query[b * 64 + tid] = part[0][tid] + part[1][tid] + part[2][tid] + part[3][tid] + mqb[tid];
}

// ---------------------------------------------------------------------------
// Head part 2: memory retrievals + MLP + sigmoid (f32 output)
// ---------------------------------------------------------------------------
__device__ void bank_topk(const float* __restrict__ K, const float* __restrict__ V,
                          int n, const float* __restrict__ W, const float* __restrict__ inn,
                          float qinv, const float* q, float* sims, float* red, int* redi,
                          float* acc64, int tid)
{
  for (int i = tid; i < n; i += 256) {
    float s = 0.f;
#pragma unroll 16
    for (int d = 0; d < 64; ++d) s += q[d] * K[(size_t)i * 64 + d];
    s *= qinv * inn[i];
    if (W) s *= W[i];
    sims[i] = s;
  }
  __syncthreads();
  for (int it = 0; it < 5; ++it) {
    float bv = -1e30f; int bi = 1 << 30;
    for (int i = tid; i < n; i += 256) {
      const float v = sims[i];
      if (v > bv) { bv = v; bi = i; }
    }
    red[tid] = bv; redi[tid] = bi;
    __syncthreads();
    for (int st = 128; st >= 1; st >>= 1) {
      if (tid < st) {
        const float v = red[tid + st]; const int ix = redi[tid + st];
        if (v > red[tid] || (v == red[tid] && ix < redi[tid])) { red[tid] = v; redi[tid] = ix; }
      }
      __syncthreads();
    }
    const int sel = redi[0];
    if (tid < 64) acc64[tid] += V[(size_t)sel * 64 + tid];
    if (tid == 0) sims[sel] = -1e30f;
    __syncthreads();
  }
}

__global__ void __launch_bounds__(256)
k_head2(const float* __restrict__ query,
        const float* extK, const float* extV,
        const float* formE, const float* concK, const float* concV,
        const float* stM, const float* ltM, const float* ltW,
        const float* infM, const float* infW,
        const float* __restrict__ inn,
        const float* rsW, const float* rsb,
        const float* gma, const float* bta,
        const float* mea, const float* vr,
        const float* outW, const float* outb,
        const float* finW, const float* finb,
        float* __restrict__ out)
{
  __shared__ float q[64];
  __shared__ float acc64[64];
  __shared__ float sims[10000];
  __shared__ float red[256];
  __shared__ int redi[256];
  __shared__ float r1[512];
  __shared__ float o2[128];

  const int b = blockIdx.x, tid = threadIdx.x;
  if (tid < 64) q[tid] = query[b * 64 + tid];
  __syncthreads();
  red[tid] = (tid < 64) ? q[tid] * q[tid] : 0.f;
  __syncthreads();
  for (int st = 128; st >= 1; st >>= 1) { if (tid < st) red[tid] += red[tid + st]; __syncthreads(); }
  const float qinv = 1.f / (sqrtf(red[0]) + 1e-6f);
  __syncthreads();

  if (tid < 100) {
    float s = 0.f;
#pragma unroll 16
    for (int d = 0; d < 64; ++d) s += q[d] * extK[(size_t)tid * 64 + d];
    sims[tid] = s;
  }
  __syncthreads();
  red[tid] = (tid < 100) ? sims[tid] : -1e30f;
  __syncthreads();
  for (int st = 128; st >= 1; st >>= 1) { if (tid < st && red[tid + st] > red[tid]) red[tid] = red[tid + st]; __syncthreads(); }
  const float mx = red[0];
  __syncthreads();
  red[tid] = (tid < 100) ? __expf(sims[tid] - mx) : 0.f;
  __syncthreads();
  for (int st = 128; st >= 1; st >>= 1) { if (tid < st) red[tid] += red[tid + st]; __syncthreads(); }
  const float Z = red[0];
  __syncthreads();
  if (tid < 100) sims[tid] = __expf(sims[tid] - mx) / Z;
  __syncthreads();
  if (tid < 64) {
    float a = 0.f;
    for (int i = 0; i < 100; ++i) a += sims[i] * extV[(size_t)i * 64 + tid];
    acc64[tid] = a;
  }
  __syncthreads();

  bank_topk(formE, formE, 1000,  nullptr, inn + 0,     qinv, q, sims, red, redi, acc64, tid);
  bank_topk(concK, concV, 1000,  nullptr, inn + 1000,  qinv, q, sims, red, redi, acc64, tid);
  bank_topk(stM,   stM,   100,   nullptr, inn + 2000,  qinv, q, sims, red, redi, acc64, tid);
  bank_topk(ltM,   ltM,   10000, ltW,     inn + 2100,  qinv, q, sims, red, redi, acc64, tid);
  bank_topk(infM,  infM,  500,   infW,    inn + 12100, qinv, q, sims, red, redi, acc64, tid);

  if (tid < 64) acc64[tid] *= (1.f / 26.f);
  __syncthreads();

  {
    const int o = tid * 2;
    float a0 = 0.f, a1 = 0.f;
#pragma unroll 16
    for (int d = 0; d < 64; ++d) {
      const float xv = acc64[d];
      a0 += xv * rsW[(size_t)d * 512 + o];
      a1 += xv * rsW[(size_t)d * 512 + o + 1];
    }
    a0 = fmaxf(a0 + rsb[o], 0.f);
    a1 = fmaxf(a1 + rsb[o + 1], 0.f);
    r1[o]     = (a0 - mea[o])     / sqrtf(vr[o]     + 1e-3f) * gma[o]     + bta[o];
    r1[o + 1] = (a1 - mea[o + 1]) / sqrtf(vr[o + 1] + 1e-3f) * gma[o + 1] + bta[o + 1];
  }
  __syncthreads();
  if (tid < 128) {
    float a = 0.f;
#pragma unroll 8
    for (int j = 0; j < 512; ++j) a += r1[j] * outW[(size_t)j * 128 + tid];
    o2[tid] = a + outb[tid];
  }
  __syncthreads();
  red[tid] = (tid < 128) ? o2[tid] * finW[tid] : 0.f;
  __syncthreads();
  for (int st = 128; st >= 1; st >>= 1) { if (tid < st) red[tid] += red[tid + st]; __syncthreads(); }
  if (tid == 0) out[b] = sigm(red[0] + finb[0]);
}

// Diagnostic: encode ws MiB as float
__global__ void k_diag(float* out, int n, float val) {
  const int i = blockIdx.x * 64 + threadIdx.x;
  if (i < n) out[i] = val;
}

// ---------------------------------------------------------------------------
// Launch
// ---------------------------------------------------------------------------
extern "C" void kernel_launch(void* const* d_in, const int* in_sizes, int n_in,
                              void* d_out, int out_size, void* d_ws, size_t ws_size,
                              hipStream_t stream)
{
  (void)in_sizes; (void)n_in;
  const int*   tokens = (const int*)d_in[0];
  const float* emb    = (const float*)d_in[1];
  const float* l1fWx  = (const float*)d_in[2];
  const float* l1fWh  = (const float*)d_in[3];
  const float* l1fb   = (const float*)d_in[4];
  const float* l1bWx  = (const float*)d_in[5];
  const float* l1bWh  = (const float*)d_in[6];
  const float* l1bb   = (const float*)d_in[7];
  const float* l2fWx  = (const float*)d_in[8];
  const float* l2fWh  = (const float*)d_in[9];
  const float* l2fb   = (const float*)d_in[10];
  const float* l2bWx  = (const float*)d_in[11];
  const float* l2bWh  = (const float*)d_in[12];
  const float* l2bb   = (const float*)d_in[13];
  const float* Wv     = (const float*)d_in[18];
  const float* bv     = (const float*)d_in[19];
  const float* Wo     = (const float*)d_in[20];
  const float* bo     = (const float*)d_in[21];
  const float* mqW    = (const float*)d_in[22];
  const float* mqb    = (const float*)d_in[23];
  const float* extK   = (const float*)d_in[24];
  const float* extV   = (const float*)d_in[25];
  const float* formE  = (const float*)d_in[26];
  const float* concK  = (const float*)d_in[27];
  const float* concV  = (const float*)d_in[28];
  const float* stM    = (const float*)d_in[29];
  const float* ltM    = (const float*)d_in[30];
  const float* ltW    = (const float*)d_in[31];
  const float* infM   = (const float*)d_in[32];
  const float* infW   = (const float*)d_in[33];
  const float* rsW    = (const float*)d_in[34];
  const float* rsb    = (const float*)d_in[35];
  const float* gma    = (const float*)d_in[36];
  const float* bta    = (const float*)d_in[37];
  const float* mea    = (const float*)d_in[38];
  const float* vr     = (const float*)d_in[39];
  const float* outW   = (const float*)d_in[40];
  const float* outb   = (const float*)d_in[41];
  const float* finW   = (const float*)d_in[42];
  const float* finb   = (const float*)d_in[43];

  float* outp = (float*)d_out;
  char* ws = (char*)d_ws;

  size_t off = 0;
  auto take = [&](size_t sz) { size_t o = off; off += (sz + 255) & ~(size_t)255; return o; };
  const size_t o_x1    = take((size_t)64 * 512 * 64 * 2);
  const size_t o_y1    = take((size_t)64 * 512 * 1024 * 2);
  const size_t o_wxt   = take((size_t)2 * 2048 * 1024 * 2);
  const size_t o_h1    = take((size_t)2 * 2 * 64 * 512 * 2);
  const size_t o_h2    = take((size_t)2 * 2 * 64 * 512 * 2);
  const size_t o_cg    = take((size_t)2 * 64 * 512 * 4);
  const size_t o_x2    = take((size_t)64 * 1024 * 2);
  const size_t o_query = take((size_t)64 * 64 * 4);
  const size_t o_norms = take((size_t)12600 * 4);
  const size_t o_flags = take(512);
  const size_t base = off;

  int CT = 0;
  const int cts[6] = {512, 256, 128, 64, 32, 16};
  for (int i = 0; i < 6; ++i) {
    const size_t need = base + (size_t)cts[i] * 524288 + 256;
    if (need <= ws_size) { CT = cts[i]; break; }
  }
  if (CT == 0) {
    k_diag<<<1, 64, 0, stream>>>(outp, out_size, (float)(ws_size >> 20));
    return;
  }
  const size_t o_zc = take((size_t)CT * 524288);

  unsigned short* x1   = (unsigned short*)(ws + o_x1);
  unsigned short* y1   = (unsigned short*)(ws + o_y1);
  unsigned short* wxt  = (unsigned short*)(ws + o_wxt);
  unsigned short* h1   = (unsigned short*)(ws + o_h1);
  unsigned short* h2   = (unsigned short*)(ws + o_h2);
  float*          cg   = (float*)(ws + o_cg);
  unsigned short* x2   = (unsigned short*)(ws + o_x2);
  float*          qry  = (float*)(ws + o_query);
  float*          nrm  = (float*)(ws + o_norms);
  int*            flags = (int*)(ws + o_flags);
  unsigned short* zcf  = (unsigned short*)(ws + o_zc);
  unsigned short* zcb  = zcf + (size_t)64 * CT * 2048;

  hipMemsetAsync(flags, 0, 512, stream);
  k_embed<<<1024, 256, 0, stream>>>(tokens, emb, x1);
  k_norms<<<50, 256, 0, stream>>>(formE, concK, stM, ltM, infM, nrm);
  k_wxt<<<dim3(16, 32, 2), 256, 0, stream>>>(l2fWx, l2bWx, wxt);

  k_lstm<1><<<64, 128, 0, stream>>>(x1, nullptr, nullptr, l1fWh, l1bWh, l1fWx, l1bWx,
                                    l1fb, l1bb, h1, y1, flags, nullptr, 0, 512, 512);

  const int nC = 512 / CT;
  for (int c = 0; c < nC; ++c) {
    const int s0 = c * CT, s1 = s0 + CT;
    k_zgemm<<<dim3(16, (64 * CT) / 128, 2), 256, 0, stream>>>(
        y1, wxt, zcf, zcb, s0, 512 - s1, CT);
    k_lstm<2><<<64, 128, 0, stream>>>(nullptr, zcf, zcb, l2fWh, l2bWh, nullptr, nullptr,
                                      l2fb, l2bb, h2, x2, flags + 64, cg, s0, s1, CT);
  }

  k_head1<<<64, 256, 0, stream>>>(x2, Wv, bv, Wo, bo, mqW, mqb, qry);
  k_head2<<<64, 256, 0, stream>>>(qry, extK, extV, formE, concK, concV, stM, ltM, ltW,
                                  infM, infW, nrm, rsW, rsb, gma, bta, mea, vr,
                                  outW, outb, finW, finb, outp);
}

// Round 8
// 7066.101 us; speedup vs baseline: 3.7217x; 2.8663x over previous
//
#include <hip/hip_runtime.h>
#include <cstddef>
#include <cstdint>

typedef short s8v   __attribute__((ext_vector_type(8)));   // 8 x bf16 bits
typedef float f32x4 __attribute__((ext_vector_type(4)));

__device__ __forceinline__ float b2f(unsigned short u) {
  union { unsigned u; float f; } x; x.u = ((unsigned)u) << 16; return x.f;
}
__device__ __forceinline__ unsigned short f2b(float f) {
  union { float f; unsigned u; } x; x.f = f;
  unsigned u = x.u;
  return (unsigned short)((u + 0x7FFFu + ((u >> 16) & 1u)) >> 16);  // RNE
}
__device__ __forceinline__ float sigm(float x) { return 1.f / (1.f + __expf(-x)); }
__device__ __forceinline__ float tanh_(float x) { return 1.f - 2.f / (__expf(2.f * x) + 1.f); }

#define AT_LOAD(p)     __hip_atomic_load((p), __ATOMIC_RELAXED, __HIP_MEMORY_SCOPE_AGENT)
#define AT_STORE_RLX(p,v) __hip_atomic_store((p), (v), __ATOMIC_RELAXED, __HIP_MEMORY_SCOPE_AGENT)

// Cache-bypass (device-coherent) 16B load/store: go straight to L3 (coherent
// point), no L2 writeback/invalidate fences needed for cross-XCD exchange.
__device__ __forceinline__ s8v ldg_b128_sc(const unsigned short* p) {
  s8v r;
  asm volatile("global_load_dwordx4 %0, %1, off sc0 sc1" : "=v"(r) : "v"(p) : "memory");
  return r;
}
__device__ __forceinline__ void stg_b128_sc(unsigned short* p, s8v v) {
  asm volatile("global_store_dwordx4 %0, %1, off sc0 sc1" :: "v"(p), "v"(v) : "memory");
}

// ---------------------------------------------------------------------------
// Embedding gather + f32->bf16
// ---------------------------------------------------------------------------
__global__ void __launch_bounds__(256)
k_embed(const int* __restrict__ tok, const float* __restrict__ emb,
        unsigned short* __restrict__ x1)
{
  const int g = blockIdx.x * 256 + threadIdx.x;
  if (g >= 64 * 512 * 8) return;
  const int row = g >> 3, i = g & 7;
  const int t = tok[row];
  const f32x4 v0 = *(const f32x4*)(emb + (size_t)t * 64 + i * 8);
  const f32x4 v1 = *(const f32x4*)(emb + (size_t)t * 64 + i * 8 + 4);
  s8v o;
#pragma unroll
  for (int e = 0; e < 4; ++e) { o[e] = (short)f2b(v0[e]); o[4 + e] = (short)f2b(v1[e]); }
  *(s8v*)(x1 + (size_t)row * 64 + i * 8) = o;
}

// Wxt[dir][n][k] = bf16(Wx2[dir][k][n])
__global__ void __launch_bounds__(256)
k_wxt(const float* __restrict__ Wf, const float* __restrict__ Wb,
      unsigned short* __restrict__ out)
{
  __shared__ float t[64][65];
  const int tid = threadIdx.x;
  const int kt = blockIdx.x, nt = blockIdx.y, dir = blockIdx.z;
  const float* W = dir ? Wb : Wf;
#pragma unroll
  for (int i = 0; i < 16; ++i) {
    const int c = i * 256 + tid;
    const int k = c >> 6, n = c & 63;
    t[k][n] = W[(size_t)(kt * 64 + k) * 2048 + nt * 64 + n];
  }
  __syncthreads();
#pragma unroll
  for (int i = 0; i < 16; ++i) {
    const int c = i * 256 + tid;
    const int n = c >> 6, k = c & 63;
    out[(size_t)dir * 2048 * 1024 + (size_t)(nt * 64 + n) * 1024 + kt * 64 + k] = f2b(t[k][n]);
  }
}

// Key inverse norms
__global__ void __launch_bounds__(256)
k_norms(const float* __restrict__ formE, const float* __restrict__ concK,
        const float* __restrict__ stM, const float* __restrict__ ltM,
        const float* __restrict__ infM, float* __restrict__ inn)
{
  const int i = blockIdx.x * 256 + threadIdx.x;
  if (i >= 12600) return;
  const float* src; int loc;
  if (i < 1000)       { src = formE; loc = i; }
  else if (i < 2000)  { src = concK; loc = i - 1000; }
  else if (i < 2100)  { src = stM;   loc = i - 2000; }
  else if (i < 12100) { src = ltM;   loc = i - 2100; }
  else                { src = infM;  loc = i - 12100; }
  float ss = 0.f;
#pragma unroll 16
  for (int d = 0; d < 64; ++d) { const float v = src[(size_t)loc * 64 + d]; ss += v * v; }
  inn[i] = 1.f / (sqrtf(ss) + 1e-6f);
}

// ---------------------------------------------------------------------------
// Persistent BiLSTM phase kernel — FENCE-FREE h exchange.
// h stores/loads bypass L1/L2 (sc0 sc1 -> coherent L3); the __syncthreads
// before the flag store drains vmcnt (write-acks at coherent point), so the
// relaxed agent flag store is ordered after all h data. No threadfence.
// ---------------------------------------------------------------------------
template<int PHASE>
__global__ void __launch_bounds__(128, 1)
k_lstm(const unsigned short* __restrict__ xin,
       const unsigned short* __restrict__ z2fp, const unsigned short* __restrict__ z2bp,
       const float* __restrict__ Whf, const float* __restrict__ Whb,
       const float* __restrict__ Wxf, const float* __restrict__ Wxb,
       const float* __restrict__ bsf, const float* __restrict__ bsb,
       unsigned short* __restrict__ hbuf,      // [dir][parity][64][512] bf16
       unsigned short* __restrict__ yout,      // P1: y1; P2: x2
       int* __restrict__ flags,                // [dir][32]
       float* __restrict__ cg,                 // [dir][64][512] f32 (phase 2)
       int s0, int s1, int CT)
{
  __shared__ unsigned short h_lds[64 * 512];   // 64KB, XOR-swizzled
  __shared__ unsigned short x_lds[64 * 64];    // 8KB  (phase 1)
  __shared__ float g_lds[2][64 * 64];          // 32KB
  __shared__ float c_lds[64 * 16];             // 4KB
  __shared__ float bias_lds[64];

  const int tid  = threadIdx.x;
  const int wv   = tid >> 6;
  const int lane = tid & 63;
  const int wg   = blockIdx.x & 31;
  const int dir  = blockIdx.x >> 5;
  const int j0   = wg * 16;
  const int fc   = lane & 15;
  const int fk   = (lane >> 4) << 3;

  const float* Wh = dir ? Whb : Whf;
  const float* Wx = dir ? Wxb : Wxf;
  const unsigned short* Z2 = dir ? z2bp : z2fp;
  const float* BS = dir ? bsb : bsf;
  int* flg = flags + dir * 32;
  unsigned short* hb = hbuf + (size_t)dir * (2 * 64 * 512);

  for (int i = tid; i < 64; i += 128) bias_lds[i] = BS[(i >> 4) * 512 + j0 + (i & 15)];
  if (PHASE == 1 || s0 == 0) {
    for (int i = tid; i < 1024; i += 128) c_lds[i] = 0.f;
  } else {
    for (int i = tid; i < 1024; i += 128)
      c_lds[i] = cg[(size_t)dir * 64 * 512 + (i >> 4) * 512 + j0 + (i & 15)];
  }

  s8v Bh[4][8];
#pragma unroll
  for (int nt = 0; nt < 4; ++nt) {
    const int col = nt * 512 + j0 + fc;
#pragma unroll
    for (int kk = 0; kk < 8; ++kk) {
      const int kb = wv * 256 + kk * 32 + fk;
      s8v f;
#pragma unroll
      for (int i = 0; i < 8; ++i) f[i] = (short)f2b(Wh[(size_t)(kb + i) * 2048 + col]);
      Bh[nt][kk] = f;
    }
  }
  s8v Bx[4];
  if (PHASE == 1) {
#pragma unroll
    for (int nt = 0; nt < 4; ++nt) {
      const int col = nt * 512 + j0 + fc;
      const int kb = wv * 32 + fk;
      s8v f;
#pragma unroll
      for (int i = 0; i < 8; ++i) f[i] = (short)f2b(Wx[(size_t)(kb + i) * 2048 + col]);
      Bx[nt] = f;
    }
  }
  __syncthreads();

  for (int s = s0; s < s1; ++s) {
    const int t = dir ? (511 - s) : s;

    s8v zreg[4];
    if (PHASE == 1) {
#pragma unroll
      for (int i = 0; i < 4; ++i) {
        const int c = i * 128 + tid;
        const int row = c >> 3, kb = c & 7;
        s8v v = *(const s8v*)(xin + ((size_t)row * 512 + t) * 64 + kb * 8);
        *(s8v*)((char*)x_lds + row * 128 + ((kb * 16) ^ ((row & 7) << 4))) = v;
      }
    } else {
      const int gb = tid >> 1, jh = tid & 1;
      const int lt = dir ? (s1 - 1 - s) : (s - s0);
#pragma unroll
      for (int g = 0; g < 4; ++g)
        zreg[g] = *(const s8v*)(Z2 + ((size_t)(gb * CT + lt)) * 2048 + g * 512 + j0 + jh * 8);
    }

    if (s > 0) {
      const int target = s;
      int spins = 0;
      for (;;) {
        int v = (lane < 32) ? AT_LOAD(&flg[lane]) : target;
        if (__all(v >= target)) break;
        if (++spins > (1 << 18)) break;      // bounded: never hang the harness
        __builtin_amdgcn_s_sleep(1);
      }
      // stage h_{s-1}: bypass loads straight from coherent L3, batched 16-deep
      const unsigned short* hsrc = hb + (size_t)((s - 1) & 1) * (64 * 512);
      s8v tmp[16];
#pragma unroll
      for (int r = 0; r < 2; ++r) {
#pragma unroll
        for (int i = 0; i < 16; ++i) {
          const int c = (r * 16 + i) * 128 + tid;
          const int row = c >> 6, kb = c & 63;
          tmp[i] = ldg_b128_sc(hsrc + (size_t)row * 512 + kb * 8);
        }
        asm volatile("s_waitcnt vmcnt(0)" ::: "memory");
        __builtin_amdgcn_sched_barrier(0);
#pragma unroll
        for (int i = 0; i < 16; ++i) {
          const int c = (r * 16 + i) * 128 + tid;
          const int row = c >> 6, kb = c & 63;
          *(s8v*)((char*)h_lds + row * 1024 + ((kb * 16) ^ ((row & 7) << 4))) = tmp[i];
        }
      }
    }
    __syncthreads();   // A

    f32x4 acc[4][4];
#pragma unroll
    for (int mt = 0; mt < 4; ++mt)
#pragma unroll
      for (int nt = 0; nt < 4; ++nt) acc[mt][nt] = (f32x4){0.f, 0.f, 0.f, 0.f};

    if (PHASE == 1) {
      const int kx2 = (wv * 32 + fk) * 2;
#pragma unroll
      for (int mt = 0; mt < 4; ++mt) {
        const int row = mt * 16 + fc;
        s8v a = *(const s8v*)((char*)x_lds + row * 128 + (kx2 ^ ((row & 7) << 4)));
#pragma unroll
        for (int nt = 0; nt < 4; ++nt)
          acc[mt][nt] = __builtin_amdgcn_mfma_f32_16x16x32_bf16(a, Bx[nt], acc[mt][nt], 0, 0, 0);
      }
    }
    if (s > 0) {
#pragma unroll
      for (int kk = 0; kk < 8; ++kk) {
        const int k2 = (wv * 256 + kk * 32 + fk) * 2;
        s8v a[4];
#pragma unroll
        for (int mt = 0; mt < 4; ++mt) {
          const int row = mt * 16 + fc;
          a[mt] = *(const s8v*)((char*)h_lds + row * 1024 + (k2 ^ ((row & 7) << 4)));
        }
#pragma unroll
        for (int mt = 0; mt < 4; ++mt)
#pragma unroll
          for (int nt = 0; nt < 4; ++nt)
            acc[mt][nt] = __builtin_amdgcn_mfma_f32_16x16x32_bf16(a[mt], Bh[nt][kk], acc[mt][nt], 0, 0, 0);
      }
    }
    {
      const int r0 = (lane >> 4) << 2;
#pragma unroll
      for (int mt = 0; mt < 4; ++mt)
#pragma unroll
        for (int nt = 0; nt < 4; ++nt) {
          const int colj = nt * 16 + fc;
          const int row0 = mt * 16 + r0;
#pragma unroll
          for (int r = 0; r < 4; ++r)
            g_lds[wv][(row0 + r) * 64 + colj] = acc[mt][nt][r];
        }
    }
    __syncthreads();   // B

    {
      const int gb = tid >> 1, jh = tid & 1;
      const float* g0 = g_lds[0] + gb * 64;
      const float* g1 = g_lds[1] + gb * 64;
      s8v hv;
#pragma unroll
      for (int jj = 0; jj < 8; ++jj) {
        const int j = jh * 8 + jj;
        float pi = g0[0 * 16 + j] + g1[0 * 16 + j] + bias_lds[0 * 16 + j];
        float pf = g0[1 * 16 + j] + g1[1 * 16 + j] + bias_lds[1 * 16 + j];
        float pg = g0[2 * 16 + j] + g1[2 * 16 + j] + bias_lds[2 * 16 + j];
        float po = g0[3 * 16 + j] + g1[3 * 16 + j] + bias_lds[3 * 16 + j];
        if (PHASE == 2) {
          pi += b2f((unsigned short)zreg[0][jj]);
          pf += b2f((unsigned short)zreg[1][jj]);
          pg += b2f((unsigned short)zreg[2][jj]);
          po += b2f((unsigned short)zreg[3][jj]);
        }
        const int ci = gb * 16 + j;
        const float c = sigm(pf) * c_lds[ci] + sigm(pi) * tanh_(pg);
        c_lds[ci] = c;
        hv[jj] = (short)f2b(sigm(po) * tanh_(c));
      }
      // publish h: bypass store to coherent L3 (no fence needed)
      stg_b128_sc(hb + (size_t)(s & 1) * (64 * 512) + gb * 512 + j0 + jh * 8, hv);
      if (PHASE == 1) {
        *(s8v*)(yout + ((size_t)gb * 512 + t) * 1024 + dir * 512 + j0 + jh * 8) = hv;
      } else if (s == 511) {
        *(s8v*)(yout + (size_t)gb * 1024 + dir * 512 + j0 + jh * 8) = hv;
      }
    }
    if (PHASE == 2 && s == s1 - 1 && s1 < 512) {
      __syncthreads();
      for (int i = tid; i < 1024; i += 128)
        cg[(size_t)dir * 64 * 512 + (i >> 4) * 512 + j0 + (i & 15)] = c_lds[i];
    }
    __syncthreads();     // C: drains vmcnt -> h stores acked at coherent point
    if (tid == 0) AT_STORE_RLX(&flg[wg], s + 1);
  }
}

// ---------------------------------------------------------------------------
// z2 chunk GEMM: (64*CT) x 2048, K=1024, 128x128 tiles
// ---------------------------------------------------------------------------
__global__ void __launch_bounds__(256)
k_zgemm(const unsigned short* __restrict__ A, const unsigned short* __restrict__ Wxt,
        unsigned short* __restrict__ Cf, unsigned short* __restrict__ Cb,
        int tb0, int tb1, int CT)
{
  __shared__ unsigned short As[128 * 64];
  __shared__ unsigned short Bs[128 * 64];
  const int tid = threadIdx.x;
  const int lane = tid & 63;
  const int w = tid >> 6;
  const int wm = w >> 1, wn = w & 1;
  const int bx = blockIdx.x, by = blockIdx.y, dz = blockIdx.z;
  const unsigned short* Bmat = Wxt + (size_t)dz * 2048 * 1024;
  unsigned short* C = dz ? Cb : Cf;
  const int tb = dz ? tb1 : tb0;
  const int fc = lane & 15, fk = (lane >> 4) << 3;

  f32x4 acc[4][4];
#pragma unroll
  for (int mt = 0; mt < 4; ++mt)
#pragma unroll
    for (int nt = 0; nt < 4; ++nt) acc[mt][nt] = (f32x4){0.f, 0.f, 0.f, 0.f};

  for (int kt = 0; kt < 16; ++kt) {
    __syncthreads();
#pragma unroll
    for (int i = 0; i < 4; ++i) {
      const int c = i * 256 + tid;
      const int row = c >> 3, kb = c & 7;
      const int m = by * 128 + row;
      const int b = m / CT, lt = m - b * CT;
      s8v v = *(const s8v*)(A + ((size_t)b * 512 + tb + lt) * 1024 + kt * 64 + kb * 8);
      *(s8v*)((char*)As + row * 128 + ((kb * 16) ^ ((row & 7) << 4))) = v;
    }
#pragma unroll
    for (int i = 0; i < 4; ++i) {
      const int c = i * 256 + tid;
      const int n = c >> 3, kb = c & 7;
      s8v v = *(const s8v*)(Bmat + (size_t)(bx * 128 + n) * 1024 + kt * 64 + kb * 8);
      *(s8v*)((char*)Bs + n * 128 + ((kb * 16) ^ ((n & 7) << 4))) = v;
    }
    __syncthreads();
#pragma unroll
    for (int kk = 0; kk < 2; ++kk) {
      const int k2 = (kk * 32 + fk) * 2;
      s8v a[4], bfr[4];
#pragma unroll
      for (int mt = 0; mt < 4; ++mt) {
        const int row = wm * 64 + mt * 16 + fc;
        a[mt] = *(const s8v*)((char*)As + row * 128 + (k2 ^ ((row & 7) << 4)));
      }
#pragma unroll
      for (int nt = 0; nt < 4; ++nt) {
        const int n = wn * 64 + nt * 16 + fc;
        bfr[nt] = *(const s8v*)((char*)Bs + n * 128 + (k2 ^ ((n & 7) << 4)));
      }
#pragma unroll
      for (int mt = 0; mt < 4; ++mt)
#pragma unroll
        for (int nt = 0; nt < 4; ++nt)
          acc[mt][nt] = __builtin_amdgcn_mfma_f32_16x16x32_bf16(a[mt], bfr[nt], acc[mt][nt], 0, 0, 0);
    }
  }
  const int r0 = (lane >> 4) << 2;
#pragma unroll
  for (int mt = 0; mt < 4; ++mt)
#pragma unroll
    for (int nt = 0; nt < 4; ++nt) {
      const size_t rowg = (size_t)(by * 128 + wm * 64 + mt * 16 + r0);
      const int colg = bx * 128 + wn * 64 + nt * 16 + fc;
#pragma unroll
      for (int r = 0; r < 4; ++r)
        C[(rowg + r) * 2048 + colg] = f2b(acc[mt][nt][r]);
    }
}

// ---------------------------------------------------------------------------
// Head part 1: S=1 attention collapses to v-proj -> Wo -> query
// ---------------------------------------------------------------------------
__global__ void __launch_bounds__(256)
k_head1(const unsigned short* __restrict__ x2,
        const float* __restrict__ Wv, const float* __restrict__ bv,
        const float* __restrict__ Wo, const float* __restrict__ bo,
        const float* __restrict__ mqW, const float* __restrict__ mqb,
        float* __restrict__ query)
{
  __shared__ float xs[1024], ys[512], x3[1024];
  __shared__ float part[4][64];
  const int b = blockIdx.x, tid = threadIdx.x;
  for (int i = tid; i < 1024; i += 256) xs[i] = b2f(x2[(size_t)b * 1024 + i]);
  __syncthreads();
  {
    const int o = tid * 2;
    float a0 = 0.f, a1 = 0.f;
#pragma unroll 8
    for (int e = 0; e < 1024; ++e) {
      const float xv = xs[e];
      a0 += xv * Wv[(size_t)e * 512 + o];
      a1 += xv * Wv[(size_t)e * 512 + o + 1];
    }
    ys[o] = a0 + bv[o];
    ys[o + 1] = a1 + bv[o + 1];
  }
  __syncthreads();
  {
    const int e0 = tid * 4;
    float a0 = 0.f, a1 = 0.f, a2 = 0.f, a3 = 0.f;
#pragma unroll 8
    for (int h = 0; h < 512; ++h) {
      const float yv = ys[h];
      a0 += yv * Wo[(size_t)h * 1024 + e0];
      a1 += yv * Wo[(size_t)h * 1024 + e0 + 1];
      a2 += yv * Wo[(size_t)h * 1024 + e0 + 2];
      a3 += yv * Wo[(size_t)h * 1024 + e0 + 3];
    }
    x3[e0] = a0 + bo[e0];
    x3[e0 + 1] = a1 + bo[e0 + 1];
    x3[e0 + 2] = a2 + bo[e0 + 2];
    x3[e0 + 3] = a3 + bo[e0 + 3];
  }
  __syncthreads();
  {
    const int o = tid & 63, kc = tid >> 6;
    float a = 0.f;
#pragma unroll 8
    for (int e = kc * 256; e < kc * 256 + 256; ++e) a += x3[e] * mqW[(size_t)e * 64 + o];
    part[kc][o] = a;
  }
  __syncthreads();
  if (tid < 64)
    query[b * 64 + tid] = part[0][tid] + part[1][tid] + part[2][tid] + part[3][tid] + mqb[tid];
}

// ---------------------------------------------------------------------------
// Head part 2: memory retrievals + MLP + sigmoid (f32 output)
// ---------------------------------------------------------------------------
__device__ void bank_topk(const float* __restrict__ K, const float* __restrict__ V,
                          int n, const float* __restrict__ W, const float* __restrict__ inn,
                          float qinv, const float* q, float* sims, float* red, int* redi,
                          float* acc64, int tid)
{
  for (int i = tid; i < n; i += 256) {
    float s = 0.f;
#pragma unroll 16
    for (int d = 0; d < 64; ++d) s += q[d] * K[(size_t)i * 64 + d];
    s *= qinv * inn[i];
    if (W) s *= W[i];
    sims[i] = s;
  }
  __syncthreads();
  for (int it = 0; it < 5; ++it) {
    float bv = -1e30f; int bi = 1 << 30;
    for (int i = tid; i < n; i += 256) {
      const float v = sims[i];
      if (v > bv) { bv = v; bi = i; }
    }
    red[tid] = bv; redi[tid] = bi;
    __syncthreads();
    for (int st = 128; st >= 1; st >>= 1) {
      if (tid < st) {
        const float v = red[tid + st]; const int ix = redi[tid + st];
        if (v > red[tid] || (v == red[tid] && ix < redi[tid])) { red[tid] = v; redi[tid] = ix; }
      }
      __syncthreads();
    }
    const int sel = redi[0];
    if (tid < 64) acc64[tid] += V[(size_t)sel * 64 + tid];
    if (tid == 0) sims[sel] = -1e30f;
    __syncthreads();
  }
}

__global__ void __launch_bounds__(256)
k_head2(const float* __restrict__ query,
        const float* extK, const float* extV,
        const float* formE, const float* concK, const float* concV,
        const float* stM, const float* ltM, const float* ltW,
        const float* infM, const float* infW,
        const float* __restrict__ inn,
        const float* rsW, const float* rsb,
        const float* gma, const float* bta,
        const float* mea, const float* vr,
        const float* outW, const float* outb,
        const float* finW, const float* finb,
        float* __restrict__ out)
{
  __shared__ float q[64];
  __shared__ float acc64[64];
  __shared__ float sims[10000];
  __shared__ float red[256];
  __shared__ int redi[256];
  __shared__ float r1[512];
  __shared__ float o2[128];

  const int b = blockIdx.x, tid = threadIdx.x;
  if (tid < 64) q[tid] = query[b * 64 + tid];
  __syncthreads();
  red[tid] = (tid < 64) ? q[tid] * q[tid] : 0.f;
  __syncthreads();
  for (int st = 128; st >= 1; st >>= 1) { if (tid < st) red[tid] += red[tid + st]; __syncthreads(); }
  const float qinv = 1.f / (sqrtf(red[0]) + 1e-6f);
  __syncthreads();

  if (tid < 100) {
    float s = 0.f;
#pragma unroll 16
    for (int d = 0; d < 64; ++d) s += q[d] * extK[(size_t)tid * 64 + d];
    sims[tid] = s;
  }
  __syncthreads();
  red[tid] = (tid < 100) ? sims[tid] : -1e30f;
  __syncthreads();
  for (int st = 128; st >= 1; st >>= 1) { if (tid < st && red[tid + st] > red[tid]) red[tid] = red[tid + st]; __syncthreads(); }
  const float mx = red[0];
  __syncthreads();
  red[tid] = (tid < 100) ? __expf(sims[tid] - mx) : 0.f;
  __syncthreads();
  for (int st = 128; st >= 1; st >>= 1) { if (tid < st) red[tid] += red[tid + st]; __syncthreads(); }
  const float Z = red[0];
  __syncthreads();
  if (tid < 100) sims[tid] = __expf(sims[tid] - mx) / Z;
  __syncthreads();
  if (tid < 64) {
    float a = 0.f;
    for (int i = 0; i < 100; ++i) a += sims[i] * extV[(size_t)i * 64 + tid];
    acc64[tid] = a;
  }
  __syncthreads();

  bank_topk(formE, formE, 1000,  nullptr, inn + 0,     qinv, q, sims, red, redi, acc64, tid);
  bank_topk(concK, concV, 1000,  nullptr, inn + 1000,  qinv, q, sims, red, redi, acc64, tid);
  bank_topk(stM,   stM,   100,   nullptr, inn + 2000,  qinv, q, sims, red, redi, acc64, tid);
  bank_topk(ltM,   ltM,   10000, ltW,     inn + 2100,  qinv, q, sims, red, redi, acc64, tid);
  bank_topk(infM,  infM,  500,   infW,    inn + 12100, qinv, q, sims, red, redi, acc64, tid);

  if (tid < 64) acc64[tid] *= (1.f / 26.f);
  __syncthreads();

  {
    const int o = tid * 2;
    float a0 = 0.f, a1 = 0.f;
#pragma unroll 16
    for (int d = 0; d < 64; ++d) {
      const float xv = acc64[d];
      a0 += xv * rsW[(size_t)d * 512 + o];
      a1 += xv * rsW[(size_t)d * 512 + o + 1];
    }
    a0 = fmaxf(a0 + rsb[o], 0.f);
    a1 = fmaxf(a1 + rsb[o + 1], 0.f);
    r1[o]     = (a0 - mea[o])     / sqrtf(vr[o]     + 1e-3f) * gma[o]     + bta[o];
    r1[o + 1] = (a1 - mea[o + 1]) / sqrtf(vr[o + 1] + 1e-3f) * gma[o + 1] + bta[o + 1];
  }
  __syncthreads();
  if (tid < 128) {
    float a = 0.f;
#pragma unroll 8
    for (int j = 0; j < 512; ++j) a += r1[j] * outW[(size_t)j * 128 + tid];
    o2[tid] = a + outb[tid];
  }
  __syncthreads();
  red[tid] = (tid < 128) ? o2[tid] * finW[tid] : 0.f;
  __syncthreads();
  for (int st = 128; st >= 1; st >>= 1) { if (tid < st) red[tid] += red[tid + st]; __syncthreads(); }
  if (tid == 0) out[b] = sigm(red[0] + finb[0]);
}

// Diagnostic: encode ws MiB as float
__global__ void k_diag(float* out, int n, float val) {
  const int i = blockIdx.x * 64 + threadIdx.x;
  if (i < n) out[i] = val;
}

// ---------------------------------------------------------------------------
// Launch
// ---------------------------------------------------------------------------
extern "C" void kernel_launch(void* const* d_in, const int* in_sizes, int n_in,
                              void* d_out, int out_size, void* d_ws, size_t ws_size,
                              hipStream_t stream)
{
  (void)in_sizes; (void)n_in;
  const int*   tokens = (const int*)d_in[0];
  const float* emb    = (const float*)d_in[1];
  const float* l1fWx  = (const float*)d_in[2];
  const float* l1fWh  = (const float*)d_in[3];
  const float* l1fb   = (const float*)d_in[4];
  const float* l1bWx  = (const float*)d_in[5];
  const float* l1bWh  = (const float*)d_in[6];
  const float* l1bb   = (const float*)d_in[7];
  const float* l2fWx  = (const float*)d_in[8];
  const float* l2fWh  = (const float*)d_in[9];
  const float* l2fb   = (const float*)d_in[10];
  const float* l2bWx  = (const float*)d_in[11];
  const float* l2bWh  = (const float*)d_in[12];
  const float* l2bb   = (const float*)d_in[13];
  const float* Wv     = (const float*)d_in[18];
  const float* bv     = (const float*)d_in[19];
  const float* Wo     = (const float*)d_in[20];
  const float* bo     = (const float*)d_in[21];
  const float* mqW    = (const float*)d_in[22];
  const float* mqb    = (const float*)d_in[23];
  const float* extK   = (const float*)d_in[24];
  const float* extV   = (const float*)d_in[25];
  const float* formE  = (const float*)d_in[26];
  const float* concK  = (const float*)d_in[27];
  const float* concV  = (const float*)d_in[28];
  const float* stM    = (const float*)d_in[29];
  const float* ltM    = (const float*)d_in[30];
  const float* ltW    = (const float*)d_in[31];
  const float* infM   = (const float*)d_in[32];
  const float* infW   = (const float*)d_in[33];
  const float* rsW    = (const float*)d_in[34];
  const float* rsb    = (const float*)d_in[35];
  const float* gma    = (const float*)d_in[36];
  const float* bta    = (const float*)d_in[37];
  const float* mea    = (const float*)d_in[38];
  const float* vr     = (const float*)d_in[39];
  const float* outW   = (const float*)d_in[40];
  const float* outb   = (const float*)d_in[41];
  const float* finW   = (const float*)d_in[42];
  const float* finb   = (const float*)d_in[43];

  float* outp = (float*)d_out;
  char* ws = (char*)d_ws;

  size_t off = 0;
  auto take = [&](size_t sz) { size_t o = off; off += (sz + 255) & ~(size_t)255; return o; };
  const size_t o_x1    = take((size_t)64 * 512 * 64 * 2);
  const size_t o_y1    = take((size_t)64 * 512 * 1024 * 2);
  const size_t o_wxt   = take((size_t)2 * 2048 * 1024 * 2);
  const size_t o_h1    = take((size_t)2 * 2 * 64 * 512 * 2);
  const size_t o_h2    = take((size_t)2 * 2 * 64 * 512 * 2);
  const size_t o_cg    = take((size_t)2 * 64 * 512 * 4);
  const size_t o_x2    = take((size_t)64 * 1024 * 2);
  const size_t o_query = take((size_t)64 * 64 * 4);
  const size_t o_norms = take((size_t)12600 * 4);
  const size_t o_flags = take(512);
  const size_t base = off;

  int CT = 0;
  const int cts[6] = {512, 256, 128, 64, 32, 16};
  for (int i = 0; i < 6; ++i) {
    const size_t need = base + (size_t)cts[i] * 524288 + 256;
    if (need <= ws_size) { CT = cts[i]; break; }
  }
  if (CT == 0) {
    k_diag<<<1, 64, 0, stream>>>(outp, out_size, (float)(ws_size >> 20));
    return;
  }
  const size_t o_zc = take((size_t)CT * 524288);

  unsigned short* x1   = (unsigned short*)(ws + o_x1);
  unsigned short* y1   = (unsigned short*)(ws + o_y1);
  unsigned short* wxt  = (unsigned short*)(ws + o_wxt);
  unsigned short* h1   = (unsigned short*)(ws + o_h1);
  unsigned short* h2   = (unsigned short*)(ws + o_h2);
  float*          cg   = (float*)(ws + o_cg);
  unsigned short* x2   = (unsigned short*)(ws + o_x2);
  float*          qry  = (float*)(ws + o_query);
  float*          nrm  = (float*)(ws + o_norms);
  int*            flags = (int*)(ws + o_flags);
  unsigned short* zcf  = (unsigned short*)(ws + o_zc);
  unsigned short* zcb  = zcf + (size_t)64 * CT * 2048;

  hipMemsetAsync(flags, 0, 512, stream);
  k_embed<<<1024, 256, 0, stream>>>(tokens, emb, x1);
  k_norms<<<50, 256, 0, stream>>>(formE, concK, stM, ltM, infM, nrm);
  k_wxt<<<dim3(16, 32, 2), 256, 0, stream>>>(l2fWx, l2bWx, wxt);

  k_lstm<1><<<64, 128, 0, stream>>>(x1, nullptr, nullptr, l1fWh, l1bWh, l1fWx, l1bWx,
                                    l1fb, l1bb, h1, y1, flags, nullptr, 0, 512, 512);

  const int nC = 512 / CT;
  for (int c = 0; c < nC; ++c) {
    const int s0 = c * CT, s1 = s0 + CT;
    k_zgemm<<<dim3(16, (64 * CT) / 128, 2), 256, 0, stream>>>(
        y1, wxt, zcf, zcb, s0, 512 - s1, CT);
    k_lstm<2><<<64, 128, 0, stream>>>(nullptr, zcf, zcb, l2fWh, l2bWh, nullptr, nullptr,
                                      l2fb, l2bb, h2, x2, flags + 64, cg, s0, s1, CT);
  }

  k_head1<<<64, 256, 0, stream>>>(x2, Wv, bv, Wo, bo, mqW, mqb, qry);
  k_head2<<<64, 256, 0, stream>>>(qry, extK, extV, formE, concK, concV, stM, ltM, ltW,
                                  infM, infW, nrm, rsW, rsb, gma, bta, mea, vr,
                                  outW, outb, finW, finb, outp);
}